// Round 7
// baseline (182.927 us; speedup 1.0000x reference)
//
#include <hip/hip_runtime.h>
#include <hip/hip_bf16.h>

typedef __attribute__((ext_vector_type(8))) short bf16x8;
typedef __attribute__((ext_vector_type(4))) float f32x4;

#define LRELU_ALPHA 0.2f

static __device__ __forceinline__ unsigned short f2bf(float x) {
    unsigned u = __float_as_uint(x);
    u += 0x7fffu + ((u >> 16) & 1u);   // RNE; inputs finite
    return (unsigned short)(u >> 16);
}
static __device__ __forceinline__ unsigned f2ord(float x) {
    unsigned b = __float_as_uint(x);
    return (b & 0x80000000u) ? ~b : (b | 0x80000000u);
}
static __device__ __forceinline__ float ord2f(unsigned m) {
    unsigned b = (m & 0x80000000u) ? (m ^ 0x80000000u) : ~m;
    return __uint_as_float(b);
}

// ---------------- Stage 0: fp32 -> bf16 ------------------------------------
__global__ __launch_bounds__(256) void k_convert(
    const float* __restrict__ x, const float* __restrict__ W,
    unsigned short* __restrict__ xb, unsigned short* __restrict__ Wb)
{
    const int bid = blockIdx.x;
    const float* src;
    unsigned short* dst;
    size_t base;
    if (bid < 1600) { src = x; dst = xb; base = (size_t)bid * 2048; }
    else            { src = W; dst = Wb; base = (size_t)(bid - 1600) * 2048; }
    const size_t idx = base + (size_t)threadIdx.x * 8;
    float4 v0 = *(const float4*)&src[idx];
    float4 v1 = *(const float4*)&src[idx + 4];
    ushort4 o0 = { f2bf(v0.x), f2bf(v0.y), f2bf(v0.z), f2bf(v0.w) };
    ushort4 o1 = { f2bf(v1.x), f2bf(v1.y), f2bf(v1.z), f2bf(v1.w) };
    *(ushort4*)&dst[idx]     = o0;
    *(ushort4*)&dst[idx + 4] = o1;
}

// ---------------- Stage 1: LDS-free bf16 MFMA GEMM, BM=16 ------------------
// grid 800 x 256 thr (4 waves); wave w covers f-slice [w*64, w*64+64).
__global__ __launch_bounds__(256) void k_gemm_fused(
    const unsigned short* __restrict__ xb, const unsigned short* __restrict__ Wb,
    const float* __restrict__ bW, const float* __restrict__ ai,
    const float* __restrict__ bi, const float* __restrict__ aj,
    const float* __restrict__ bj,
    unsigned short* __restrict__ WhT, float* __restrict__ Wh1,
    float* __restrict__ Wh2, unsigned* __restrict__ M2g)
{
    __shared__ float part1[4][16], part2[4][16];
    const int t = threadIdx.x;
    const int w = t >> 6, l = t & 63;
    const int R0 = blockIdx.x * 16;
    const int arow = R0 + (l & 15);
    const int kg8 = (l >> 4) * 8;

    f32x4 acc[4];
#pragma unroll
    for (int nf = 0; nf < 4; ++nf) acc[nf] = (f32x4){0.f,0.f,0.f,0.f};

#pragma unroll
    for (int k0 = 0; k0 < 256; k0 += 32) {
        bf16x8 af = *(const bf16x8*)&xb[(size_t)arow*256 + k0 + kg8];
#pragma unroll
        for (int nf = 0; nf < 4; ++nf) {
            bf16x8 bfv = *(const bf16x8*)&Wb[(size_t)(w*64 + nf*16 + (l&15))*256 + k0 + kg8];
            acc[nf] = __builtin_amdgcn_mfma_f32_16x16x32_bf16(af, bfv, acc[nf], 0, 0, 0);
        }
    }

    const int b   = R0 / 1600;
    const int n0b = R0 - b*1600;
    const int rowg = (l >> 4) * 4;
    float p1[4] = {0,0,0,0}, p2[4] = {0,0,0,0};
#pragma unroll
    for (int nf = 0; nf < 4; ++nf) {
        const int f = w*64 + nf*16 + (l & 15);
        const float bwv = bW[f], aiv = ai[f], ajv = aj[f];
        float vv[4];
#pragma unroll
        for (int e = 0; e < 4; ++e) {
            float v = acc[nf][e] + bwv;
            vv[e] = v;
            p1[e] = __builtin_fmaf(v, aiv, p1[e]);
            p2[e] = __builtin_fmaf(v, ajv, p2[e]);
        }
        ushort4 o4 = { f2bf(vv[0]), f2bf(vv[1]), f2bf(vv[2]), f2bf(vv[3]) };
        *(ushort4*)&WhT[((size_t)(b*256 + f))*1600 + n0b + rowg] = o4;
    }
#pragma unroll
    for (int m = 1; m < 16; m <<= 1)
#pragma unroll
        for (int e = 0; e < 4; ++e) {
            p1[e] += __shfl_xor(p1[e], m, 64);
            p2[e] += __shfl_xor(p2[e], m, 64);
        }
    if ((l & 15) == 0)
#pragma unroll
        for (int e = 0; e < 4; ++e) {
            part1[w][rowg + e] = p1[e];
            part2[w][rowg + e] = p2[e];
        }
    __syncthreads();
    if (t < 16) {
        float v1 = part1[0][t]+part1[1][t]+part1[2][t]+part1[3][t] + bi[0];
        float v2 = part2[0][t]+part2[1][t]+part2[2][t]+part2[3][t] + bj[0];
        Wh1[R0 + t] = v1;
        Wh2[R0 + t] = v2;
        unsigned o = f2ord(v2);
#pragma unroll
        for (int m = 1; m < 16; m <<= 1) {
            unsigned o2 = __shfl_xor(o, m, 64);
            o = (o2 > o) ? o2 : o;
        }
        if (t == 0) atomicMax(&M2g[b], o);
    }
}

// ---------------- Stage 2: j-split pipelined fixed-m flash attention -------
// grid 800: b = bid&7 (XCD), r3=bid>>3: js = r3/50, i0 = (r3%50)*32.
// 512 thr = 8 waves; wave w: scores rows w*4..+3, PV f-slice [w*32,+32).
// Unroll-2 named prefetch sets -> compiler-counted vmcnt, no per-tile drain.
// Writes fp32 partial O and partial l (fixed m => partials additive).
struct Tile { bf16x8 B[2][2]; int a[4]; float wv; };

static __device__ __forceinline__ void load_tile(
    Tile& S, int jt, const unsigned short* bp0, const unsigned short* bp1,
    const int* ap, const float* wh2p, int w)
{
    const int j0 = jt * 64;
    S.B[0][0] = *(const bf16x8*)(bp0 + j0);
    S.B[0][1] = *(const bf16x8*)(bp0 + j0 + 32);
    S.B[1][0] = *(const bf16x8*)(bp1 + j0);
    S.B[1][1] = *(const bf16x8*)(bp1 + j0 + 32);
#pragma unroll
    for (int r = 0; r < 4; ++r)
        S.a[r] = ap[(size_t)(w*4 + r)*1600 + j0];
    S.wv = wh2p[j0];
}

static __device__ __forceinline__ void comp_tile(
    const Tile& S, unsigned short* pb, const float* wh1r, const float* mr,
    float* lsum, f32x4 (&acc)[2][2], int w, int l)
{
#pragma unroll
    for (int r = 0; r < 4; ++r) {
        const int row = w*4 + r;
        float s = wh1r[r] + S.wv;
        s = s > 0.f ? s : LRELU_ALPHA * s;
        float p = (S.a[r] > 0) ? __expf(s - mr[r]) : 0.f;
        lsum[r] += p;
        int off = (row*128 + l*2) ^ ((row & 7) << 4);
        *(unsigned short*)((char*)pb + off) = f2bf(p);
    }
    asm volatile("s_waitcnt lgkmcnt(0)" ::: "memory");
    __builtin_amdgcn_sched_barrier(0);
    __builtin_amdgcn_s_barrier();
#pragma unroll
    for (int kb = 0; kb < 2; ++kb) {
        bf16x8 af[2];
#pragma unroll
        for (int mi = 0; mi < 2; ++mi) {
            int ar = mi*16 + (l & 15);
            int aoff = (ar*128 + kb*64 + (l>>4)*16) ^ ((ar & 7) << 4);
            af[mi] = *(const bf16x8*)((const char*)pb + aoff);
        }
#pragma unroll
        for (int mi = 0; mi < 2; ++mi)
#pragma unroll
            for (int nf = 0; nf < 2; ++nf)
                acc[mi][nf] = __builtin_amdgcn_mfma_f32_16x16x32_bf16(
                    af[mi], S.B[nf][kb], acc[mi][nf], 0, 0, 0);
    }
}

__global__ __launch_bounds__(512) void k_attn(
    const unsigned short* __restrict__ WhT,
    const float* __restrict__ Wh1, const unsigned* __restrict__ M2g,
    const float* __restrict__ Wh2, const int* __restrict__ adj,
    float* __restrict__ Oacc, float* __restrict__ Lacc)
{
    __shared__ alignas(16) unsigned short pls[2][32*64];

    const int t = threadIdx.x;
    const int w = t >> 6, l = t & 63;
    const int b  = blockIdx.x & 7;
    const int r3 = blockIdx.x >> 3;          // 0..99
    const int js = (r3 >= 50) ? 1 : 0;
    const int gx = r3 - js*50;               // 0..49
    const int i0 = gx * 32;
    const int ggid = b*50 + gx;
    const int t0   = js ? 13 : 0;
    const int tend = js ? 25 : 13;

    const float m2v = ord2f(M2g[b]);
    float wh1r[4], mr[4];
#pragma unroll
    for (int r = 0; r < 4; ++r) {
        int gi = i0 + w*4 + r;
        wh1r[r] = Wh1[b*1600 + gi];
        float s = wh1r[r] + m2v;
        mr[r] = s > 0.f ? s : LRELU_ALPHA * s;
    }
    float lsum[4] = {0.f,0.f,0.f,0.f};
    f32x4 acc[2][2];
#pragma unroll
    for (int mi = 0; mi < 2; ++mi)
#pragma unroll
        for (int nf = 0; nf < 2; ++nf) acc[mi][nf] = (f32x4){0.f,0.f,0.f,0.f};

    const unsigned short* whtb = WhT + (size_t)b*256*1600;
    const unsigned short* bp0 = whtb + (size_t)(w*32 +  0 + (l&15))*1600 + (l>>4)*8;
    const unsigned short* bp1 = whtb + (size_t)(w*32 + 16 + (l&15))*1600 + (l>>4)*8;
    const int*   ap   = adj + (size_t)i0*1600 + l;
    const float* wh2p = Wh2 + b*1600 + l;

    Tile S0, S1;
    load_tile(S0, t0, bp0, bp1, ap, wh2p, w);
    int jt = t0;
    for (; jt + 1 < tend; jt += 2) {
        load_tile(S1, jt + 1, bp0, bp1, ap, wh2p, w);
        __builtin_amdgcn_sched_barrier(0);
        comp_tile(S0, pls[0], wh1r, mr, lsum, acc, w, l);
        if (jt + 2 < tend) load_tile(S0, jt + 2, bp0, bp1, ap, wh2p, w);
        __builtin_amdgcn_sched_barrier(0);
        comp_tile(S1, pls[1], wh1r, mr, lsum, acc, w, l);
    }
    if (jt < tend)
        comp_tile(S0, pls[0], wh1r, mr, lsum, acc, w, l);

    // partial l: reduce across 64 lanes, write once
#pragma unroll
    for (int s2 = 1; s2 < 64; s2 <<= 1)
#pragma unroll
        for (int r = 0; r < 4; ++r)
            lsum[r] += __shfl_xor(lsum[r], s2, 64);
    if (l == 0)
#pragma unroll
        for (int r = 0; r < 4; ++r)
            Lacc[js*12800 + ggid*32 + w*4 + r] = lsum[r];

    // partial O: fp32 store (no normalize here)
    float* ob = Oacc + ((size_t)js*400 + ggid) * 8192;
#pragma unroll
    for (int mi = 0; mi < 2; ++mi)
#pragma unroll
        for (int e = 0; e < 4; ++e) {
            const int row = mi*16 + (l>>4)*4 + e;
#pragma unroll
            for (int nf = 0; nf < 2; ++nf)
                ob[row*256 + w*32 + nf*16 + (l & 15)] = acc[mi][nf][e];
        }
}

// ---------------- Stage 3: combine halves, normalize, ELU ------------------
__global__ __launch_bounds__(256) void k_final(
    const float* __restrict__ Oacc, const float* __restrict__ Lacc,
    float* __restrict__ out)
{
    const int g = blockIdx.x;                 // 0..399 = b*50 + i0/32
    const int b = g / 50, i0 = (g % 50) * 32;
    const int t = threadIdx.x;
    const int row = t >> 3, f0 = (t & 7) * 32;
    const float L = Lacc[g*32 + row] + Lacc[12800 + g*32 + row];
    const float rl = 1.f / L;
    const float* o0 = Oacc + (size_t)g*8192 + row*256 + f0;
    const float* o1 = o0 + 3276800;
    float* op = out + ((size_t)(b*1600 + i0 + row))*256 + f0;
#pragma unroll
    for (int q = 0; q < 8; ++q) {
        float4 a = *(const float4*)&o0[q*4];
        float4 c = *(const float4*)&o1[q*4];
        float v0 = (a.x + c.x) * rl, v1 = (a.y + c.y) * rl;
        float v2 = (a.z + c.z) * rl, v3 = (a.w + c.w) * rl;
        float4 r;
        r.x = v0 > 0.f ? v0 : expm1f(v0);
        r.y = v1 > 0.f ? v1 : expm1f(v1);
        r.z = v2 > 0.f ? v2 : expm1f(v2);
        r.w = v3 > 0.f ? v3 : expm1f(v3);
        *(float4*)&op[q*4] = r;
    }
}

extern "C" void kernel_launch(void* const* d_in, const int* in_sizes, int n_in,
                              void* d_out, int out_size, void* d_ws, size_t ws_size,
                              hipStream_t stream)
{
    const float* h  = (const float*)d_in[0];
    const int* adj  = (const int*)d_in[1];
    const float* W  = (const float*)d_in[2];
    const float* bW = (const float*)d_in[3];
    const float* ai = (const float*)d_in[4];
    const float* bi = (const float*)d_in[5];
    const float* aj = (const float*)d_in[6];
    const float* bj = (const float*)d_in[7];
    float* out = (float*)d_out;

    char* ws = (char*)d_ws;
    unsigned short* xb  = (unsigned short*)ws;                    // 6,553,600 B
    unsigned short* Wb  = (unsigned short*)(ws + 6553600);        //   131,072 B
    unsigned short* WhT = (unsigned short*)(ws + 6684672);        // 6,553,600 B
    float* Wh1 = (float*)(ws + 13238272);                         //    51,200 B
    float* Wh2 = (float*)(ws + 13289472);                         //    51,200 B
    unsigned* M2g = (unsigned*)(ws + 13340672);                   //        32 B
    float* Oacc = (float*)(ws + 13340800);                        // 26,214,400 B
    float* Lacc = (float*)(ws + 39555200);                        //   102,400 B

    hipMemsetAsync(M2g, 0, 32, stream);
    k_convert<<<1632, 256, 0, stream>>>(h, W, xb, Wb);
    k_gemm_fused<<<800, 256, 0, stream>>>(xb, Wb, bW, ai, bi, aj, bj,
                                          WhT, Wh1, Wh2, M2g);
    k_attn<<<800, 512, 0, stream>>>(WhT, Wh1, M2g, Wh2, adj, Oacc, Lacc);
    k_final<<<400, 256, 0, stream>>>(Oacc, Lacc, out);
}

// Round 11
// 171.394 us; speedup vs baseline: 1.0673x; 1.0673x over previous
//
#include <hip/hip_runtime.h>
#include <hip/hip_bf16.h>

typedef __attribute__((ext_vector_type(8))) short bf16x8;
typedef __attribute__((ext_vector_type(4))) float f32x4;

#define ALPHA 0.2f
#define L2E 1.4426950408889634f

static __device__ __forceinline__ unsigned short f2bf(float x) {
    unsigned u = __float_as_uint(x);
    u += 0x7fffu + ((u >> 16) & 1u);   // RNE
    return (unsigned short)(u >> 16);
}
static __device__ __forceinline__ unsigned f2ord(float x) {
    unsigned b = __float_as_uint(x);
    return (b & 0x80000000u) ? ~b : (b | 0x80000000u);
}
static __device__ __forceinline__ float ord2f(unsigned m) {
    unsigned b = (m & 0x80000000u) ? (m ^ 0x80000000u) : ~m;
    return __uint_as_float(b);
}

// ---------- k_prep: W fp32->bf16 (bid<32) + adj bitmask (200 blocks) -------
__global__ __launch_bounds__(256) void k_prep(
    const float* __restrict__ W, const int* __restrict__ adj,
    unsigned short* __restrict__ Wb, unsigned* __restrict__ bm)
{
    const int bid = blockIdx.x, t = threadIdx.x;
    if (bid < 32) {
        const size_t idx = (size_t)bid * 2048 + (size_t)t * 8;
        float4 v0 = *(const float4*)&W[idx];
        float4 v1 = *(const float4*)&W[idx + 4];
        ushort4 o0 = { f2bf(v0.x), f2bf(v0.y), f2bf(v0.z), f2bf(v0.w) };
        ushort4 o1 = { f2bf(v1.x), f2bf(v1.y), f2bf(v1.z), f2bf(v1.w) };
        *(ushort4*)&Wb[idx]     = o0;
        *(ushort4*)&Wb[idx + 4] = o1;
    } else {
        const int w = t >> 6, l = t & 63;
        const int row0 = (bid - 32) * 8 + w * 2;
#pragma unroll
        for (int rr = 0; rr < 2; ++rr) {
            const int row = row0 + rr;
            for (int ps = 0; ps < 25; ++ps) {
                int a = adj[(size_t)row * 1600 + ps * 64 + l];
                unsigned long long mask = __ballot(a > 0);
                if (l == 0) {
                    bm[row * 50 + ps * 2]     = (unsigned)mask;
                    bm[row * 50 + ps * 2 + 1] = (unsigned)(mask >> 32);
                }
            }
        }
    }
}

// ---------- k_gemm: Wh=x@W^T+bW via bf16 MFMA (x converted in-reg) ---------
// grid 200 x 256thr; BM=64; wave w owns rows R0+w*16, all 256 f.
// Stores WhT[b][f][n] bf16; W1L/W2L = (dot+bias)*log2e; M2g[b] atomic max.
__global__ __launch_bounds__(256) void k_gemm(
    const float* __restrict__ x, const unsigned short* __restrict__ Wb,
    const float* __restrict__ bW, const float* __restrict__ ai,
    const float* __restrict__ bi, const float* __restrict__ aj,
    const float* __restrict__ bj,
    unsigned short* __restrict__ WhT, float* __restrict__ W1L,
    float* __restrict__ W2L, unsigned* __restrict__ M2g)
{
    const int t = threadIdx.x, w = t >> 6, l = t & 63;
    const int R0 = blockIdx.x * 64;
    const int rA = R0 + w * 16 + (l & 15);
    const int kg = (l >> 4) * 8;

    f32x4 acc[16];
#pragma unroll
    for (int nf = 0; nf < 16; ++nf) acc[nf] = (f32x4){0.f, 0.f, 0.f, 0.f};

#pragma unroll
    for (int k0 = 0; k0 < 256; k0 += 32) {
        float4 a0 = *(const float4*)&x[(size_t)rA * 256 + k0 + kg];
        float4 a1 = *(const float4*)&x[(size_t)rA * 256 + k0 + kg + 4];
        union { bf16x8 v; __hip_bfloat162 h[4]; } ua;
        ua.h[0] = __float22bfloat162_rn(make_float2(a0.x, a0.y));
        ua.h[1] = __float22bfloat162_rn(make_float2(a0.z, a0.w));
        ua.h[2] = __float22bfloat162_rn(make_float2(a1.x, a1.y));
        ua.h[3] = __float22bfloat162_rn(make_float2(a1.z, a1.w));
        bf16x8 af = ua.v;
#pragma unroll
        for (int nf = 0; nf < 16; ++nf) {
            bf16x8 bv = *(const bf16x8*)&Wb[(size_t)(nf * 16 + (l & 15)) * 256 + k0 + kg];
            acc[nf] = __builtin_amdgcn_mfma_f32_16x16x32_bf16(af, bv, acc[nf], 0, 0, 0);
        }
    }

    const int b = blockIdx.x / 25;
    const int nloc = R0 - b * 1600 + w * 16 + (l >> 4) * 4;
    float p1[4] = {0, 0, 0, 0}, p2[4] = {0, 0, 0, 0};
#pragma unroll
    for (int nf = 0; nf < 16; ++nf) {
        const int f = nf * 16 + (l & 15);
        const float bwv = bW[f], aiv = ai[f], ajv = aj[f];
        float vv[4];
#pragma unroll
        for (int e = 0; e < 4; ++e) {
            float v = acc[nf][e] + bwv;
            vv[e] = v;
            p1[e] = __builtin_fmaf(v, aiv, p1[e]);
            p2[e] = __builtin_fmaf(v, ajv, p2[e]);
        }
        ushort4 o4 = { f2bf(vv[0]), f2bf(vv[1]), f2bf(vv[2]), f2bf(vv[3]) };
        *(ushort4*)&WhT[((size_t)(b * 256 + f)) * 1600 + nloc] = o4;
    }
#pragma unroll
    for (int m = 1; m < 16; m <<= 1)
#pragma unroll
        for (int e = 0; e < 4; ++e) {
            p1[e] += __shfl_xor(p1[e], m, 64);
            p2[e] += __shfl_xor(p2[e], m, 64);
        }
    const float biv = bi[0], bjv = bj[0];
    float v2s[4];
#pragma unroll
    for (int e = 0; e < 4; ++e) v2s[e] = (p2[e] + bjv) * L2E;
    if ((l & 15) == 0) {
#pragma unroll
        for (int e = 0; e < 4; ++e) {
            int n = R0 + w * 16 + (l >> 4) * 4 + e;
            W1L[n] = (p1[e] + biv) * L2E;
            W2L[n] = v2s[e];
        }
    }
    float m2 = fmaxf(fmaxf(v2s[0], v2s[1]), fmaxf(v2s[2], v2s[3]));
    m2 = fmaxf(m2, __shfl_xor(m2, 16, 64));
    m2 = fmaxf(m2, __shfl_xor(m2, 32, 64));
    if (l == 0) atomicMax(&M2g[b], f2ord(m2));
}

// ---------- k_attn: fixed-m flash attention, P in registers ----------------
// grid 208: b=bid&7 (XCD), it=(bid>>3)>>1 (128-row i-tile), fs=(bid>>3)&1.
// 512 thr = 8 waves; wave w owns 16 i-rows, f-slice fs*128 (8 nf).
// Scores computed directly in A-fragment layout; B triple-buffered in LDS
// via global_load_lds (R1-verified swizzle); ONE s_barrier per 64-j tile.
struct Pref { float4 w2[2][2]; uint2 q; };

static __device__ __forceinline__ void prefetchT(
    Pref& P, int jt, const float* __restrict__ w2lp,
    const unsigned char* __restrict__ bmrow, int l)
{
    const int g = (l >> 4) * 8;
#pragma unroll
    for (int kb = 0; kb < 2; ++kb) {
        P.w2[kb][0] = *(const float4*)&w2lp[jt * 64 + kb * 32 + g];
        P.w2[kb][1] = *(const float4*)&w2lp[jt * 64 + kb * 32 + g + 4];
    }
    P.q = *(const uint2*)&bmrow[jt * 8];
}

static __device__ __forceinline__ void stageT(
    unsigned short* buf, int jt, const unsigned short* __restrict__ src,
    int w, int l)
{
#pragma unroll
    for (int q = 0; q < 2; ++q) {
        const int f_loc = q * 64 + w * 8 + (l >> 3);
        const int cs = (l & 7) ^ ((l >> 3) & 7);
        const unsigned short* g = src + (size_t)f_loc * 1600 + jt * 64 + cs * 8;
        __builtin_amdgcn_global_load_lds(
            (const __attribute__((address_space(1))) unsigned int*)g,
            (__attribute__((address_space(3))) unsigned int*)(buf + q * 4096 + w * 512),
            16, 0, 0);
    }
    __builtin_amdgcn_sched_barrier(0);   // keep stage issue before later loads
}

static __device__ __forceinline__ void scoresT(
    const Pref& P, float W1Lv, float mL, int l, bf16x8 af[2], float& lsum)
{
#pragma unroll
    for (int kb = 0; kb < 2; ++kb) {
        const unsigned byte = ((kb ? P.q.y : P.q.x) >> ((l >> 4) * 8)) & 0xffu;
        float pf[8];
#pragma unroll
        for (int e = 0; e < 8; ++e) {
            float w2 = ((const float*)&P.w2[kb][e >> 2])[e & 3];
            float s = W1Lv + w2;
            s = fmaxf(s, ALPHA * s);      // LeakyReLU (scale-commutes)
            float pm = exp2f(s - mL);
            float p = ((byte >> e) & 1u) ? pm : 0.f;
            lsum += p;
            pf[e] = p;
        }
        union { bf16x8 v; __hip_bfloat162 h[4]; } u;
#pragma unroll
        for (int e2 = 0; e2 < 4; ++e2)
            u.h[e2] = __float22bfloat162_rn(make_float2(pf[2 * e2], pf[2 * e2 + 1]));
        af[kb] = u.v;
    }
}

static __device__ __forceinline__ void pvT(
    const unsigned short* buf, const bf16x8 af[2], f32x4* acc, int l)
{
    __builtin_amdgcn_sched_barrier(0);
    __builtin_amdgcn_s_barrier();
    __builtin_amdgcn_sched_barrier(0);
#pragma unroll
    for (int kb = 0; kb < 2; ++kb)
#pragma unroll
        for (int nf = 0; nf < 8; ++nf) {
            const int f_loc = nf * 16 + (l & 15);
            const int byte = f_loc * 128 + ((kb * 64 + (l >> 4) * 16) ^ ((f_loc & 7) << 4));
            bf16x8 bv = *(const bf16x8*)((const char*)buf + byte);
            acc[nf] = __builtin_amdgcn_mfma_f32_16x16x32_bf16(af[kb], bv, acc[nf], 0, 0, 0);
        }
}

__global__ __launch_bounds__(512) void k_attn(
    const unsigned short* __restrict__ WhT, const float* __restrict__ W1L,
    const float* __restrict__ W2L, const unsigned* __restrict__ M2g,
    const unsigned char* __restrict__ bmb, float* __restrict__ out)
{
    __shared__ alignas(16) unsigned short bufs[3][8192];

    const int t = threadIdx.x, w = t >> 6, l = t & 63;
    const int b = blockIdx.x & 7;
    const int r = blockIdx.x >> 3;
    const int it = r >> 1, fs = r & 1;
    const int i0 = it * 128;

    const int i_loc = i0 + w * 16 + (l & 15);
    const int i_eff = i_loc < 1600 ? i_loc : 1599;
    const float W1Lv = W1L[b * 1600 + i_eff];
    const float M2Lv = ord2f(M2g[b]);
    float mlt = W1Lv + M2Lv;
    const float mL = fmaxf(mlt, ALPHA * mlt);   // >= scaled row max

    const unsigned short* src = WhT + (size_t)(b * 256 + fs * 128) * 1600;
    const float* w2lp = W2L + b * 1600;
    const unsigned char* bmrow = bmb + (size_t)i_eff * 200;

    f32x4 acc[8];
#pragma unroll
    for (int nf = 0; nf < 8; ++nf) acc[nf] = (f32x4){0.f, 0.f, 0.f, 0.f};
    float lsum = 0.f;
    bf16x8 af[2];
    Pref PA, PB, PC;

    stageT(bufs[0], 0, src, w, l);
    prefetchT(PA, 0, w2lp, bmrow, l);

    int jt = 0;
#pragma unroll 1
    for (int u = 0; u < 8; ++u) {
        stageT(bufs[1], jt + 1, src, w, l);
        prefetchT(PB, jt + 1, w2lp, bmrow, l);
        scoresT(PA, W1Lv, mL, l, af, lsum);
        pvT(bufs[0], af, acc, l);

        stageT(bufs[2], jt + 2, src, w, l);
        prefetchT(PC, jt + 2, w2lp, bmrow, l);
        scoresT(PB, W1Lv, mL, l, af, lsum);
        pvT(bufs[1], af, acc, l);

        stageT(bufs[0], jt + 3, src, w, l);          // u=7 stages jt=24
        prefetchT(PA, jt + 3, w2lp, bmrow, l);
        scoresT(PC, W1Lv, mL, l, af, lsum);
        pvT(bufs[2], af, acc, l);
        jt += 3;
    }
    // tail jt = 24
    scoresT(PA, W1Lv, mL, l, af, lsum);
    pvT(bufs[0], af, acc, l);

    // row sums: lane covers j with (j>>3)&3 == l>>4 -> reduce over groups
    lsum += __shfl_xor(lsum, 16, 64);
    lsum += __shfl_xor(lsum, 32, 64);

    if (i0 + w * 16 < 1600) {
        float* op = out + ((size_t)b * 1600 + i0 + w * 16) * 256 + fs * 128;
#pragma unroll
        for (int e = 0; e < 4; ++e) {
            const int rowl = (l >> 4) * 4 + e;
            const float L = __shfl(lsum, rowl, 64);   // lanes 0..15 hold rows
            const float rl = 1.f / L;
#pragma unroll
            for (int nf = 0; nf < 8; ++nf) {
                float v = acc[nf][e] * rl;
                v = v > 0.f ? v : expm1f(v);
                op[(size_t)rowl * 256 + nf * 16 + (l & 15)] = v;
            }
        }
    }
}

extern "C" void kernel_launch(void* const* d_in, const int* in_sizes, int n_in,
                              void* d_out, int out_size, void* d_ws, size_t ws_size,
                              hipStream_t stream)
{
    const float* h  = (const float*)d_in[0];
    const int* adj  = (const int*)d_in[1];
    const float* W  = (const float*)d_in[2];
    const float* bW = (const float*)d_in[3];
    const float* ai = (const float*)d_in[4];
    const float* bi = (const float*)d_in[5];
    const float* aj = (const float*)d_in[6];
    const float* bj = (const float*)d_in[7];
    float* out = (float*)d_out;

    char* ws = (char*)d_ws;
    unsigned short* Wb  = (unsigned short*)ws;              //   131,072 B
    unsigned*       bm  = (unsigned*)(ws + 131072);         //   320,000 B
    unsigned short* WhT = (unsigned short*)(ws + 451072);   // 6,553,600 B
    float* W1L = (float*)(ws + 7004672);                    //    51,200 B
    float* W2L = (float*)(ws + 7055872);                    //    51,200 B
    unsigned* M2g = (unsigned*)(ws + 7107072);              //        32 B

    hipMemsetAsync(M2g, 0, 32, stream);   // ordered-uint -inf
    k_prep<<<232, 256, 0, stream>>>(W, adj, Wb, bm);
    k_gemm<<<200, 256, 0, stream>>>(h, Wb, bW, ai, bi, aj, bj, WhT, W1L, W2L, M2g);
    k_attn<<<208, 512, 0, stream>>>(WhT, W1L, W2L, M2g, (const unsigned char*)bm, out);
}